// Round 1
// baseline (269.863 us; speedup 1.0000x reference)
//
#include <hip/hip_runtime.h>

#define M 32          // number of LPC coeffs (a has M+1 = 33 per row)
#define NC 33         // elements per row
#define TPB 256       // threads (rows) per block
#define PAD 34        // padded LDS row stride (floats)

__global__ __launch_bounds__(TPB)
void lpc_to_parcor_kernel(const float* __restrict__ a,
                          float* __restrict__ out,
                          long long nrows) {
    __shared__ float lds[TPB * PAD];

    const int t = threadIdx.x;
    const long long row0 = (long long)blockIdx.x * TPB;
    const long long base = row0 * NC;
    const long long limit = nrows * NC;

    // --- coalesced global -> LDS (de-interleave rows, +1 pad) ---
    #pragma unroll
    for (int k = 0; k < NC; ++k) {
        int g = t + k * TPB;                 // 0 .. 256*33-1
        long long ga = base + g;
        float v = (ga < limit) ? a[ga] : 0.0f;
        int r = g / NC;
        int c = g - r * NC;
        lds[r * PAD + c] = v;
    }
    __syncthreads();

    // --- per-thread Levinson step-down, all in registers ---
    float ar[M];
    #pragma unroll
    for (int j = 0; j < M; ++j) ar[j] = lds[t * PAD + 1 + j];   // GAMMA == 1.0

    // out[0] = K = a[...,0] : lds slot t*PAD+0 already holds it, leave as-is.
    #pragma unroll
    for (int m = M - 1; m >= 1; --m) {
        float km = ar[m];
        lds[t * PAD + m + 1] = km;          // out[..., m+1] = km
        float rz = 1.0f / (1.0f - km * km);
        float tmp[M];
        #pragma unroll
        for (int j = 0; j < m; ++j)
            tmp[j] = (ar[j] - km * ar[m - 1 - j]) * rz;
        #pragma unroll
        for (int j = 0; j < m; ++j)
            ar[j] = tmp[j];
    }
    lds[t * PAD + 1] = ar[0];               // out[..., 1] = k0

    __syncthreads();

    // --- coalesced LDS -> global ---
    #pragma unroll
    for (int k = 0; k < NC; ++k) {
        int g = t + k * TPB;
        long long ga = base + g;
        if (ga < limit) {
            int r = g / NC;
            int c = g - r * NC;
            out[ga] = lds[r * PAD + c];
        }
    }
}

extern "C" void kernel_launch(void* const* d_in, const int* in_sizes, int n_in,
                              void* d_out, int out_size, void* d_ws, size_t ws_size,
                              hipStream_t stream) {
    const float* a = (const float*)d_in[0];
    float* out = (float*)d_out;
    long long nrows = (long long)in_sizes[0] / NC;
    int blocks = (int)((nrows + TPB - 1) / TPB);
    lpc_to_parcor_kernel<<<blocks, TPB, 0, stream>>>(a, out, nrows);
}

// Round 3
// 109.356 us; speedup vs baseline: 2.4678x; 2.4678x over previous
//
#include <hip/hip_runtime.h>

#define M 32                       // number of reflection coeffs
#define NC 33                      // floats per row (K + 32 coeffs)
#define TPB 128                    // threads (rows) per block
#define FPB (TPB * NC)             // floats per block = 4224
#define V4_ROUNDS 8                // 8*128 float4 = 4096 floats; +128 scalar tail

__global__ __launch_bounds__(TPB)
void lpc_to_parcor_kernel(const float* __restrict__ a,
                          float* __restrict__ out,
                          long long nrows) {
    __shared__ float lds[FPB];     // stride NC==33: linear copy, 2-way-free banks

    const int t = threadIdx.x;
    const long long base = (long long)blockIdx.x * FPB;
    const long long limit = nrows * NC;
    const bool full = (base + FPB) <= limit;

    // --- coalesced global -> LDS, vectorized ---
    if (full) {
        const float4* a4 = (const float4*)(a + base);   // base*4 bytes, 16B-aligned
        float4* lds4 = (float4*)lds;
        #pragma unroll
        for (int k = 0; k < V4_ROUNDS; ++k)
            lds4[t + k * TPB] = a4[t + k * TPB];
        lds[V4_ROUNDS * 4 * TPB + t] = a[base + V4_ROUNDS * 4 * TPB + t];
    } else {
        for (int k = 0; k < NC; ++k) {
            int g = t + k * TPB;
            long long ga = base + g;
            lds[g] = (ga < limit) ? a[ga] : 0.0f;
        }
    }
    __syncthreads();

    // --- per-thread Levinson step-down, registers only ---
    const int rb = t * NC;
    float ar[M];
    #pragma unroll
    for (int j = 0; j < M; ++j) ar[j] = lds[rb + 1 + j];   // GAMMA == 1.0

    #pragma unroll
    for (int m = M - 1; m >= 1; --m) {
        float km = ar[m];
        lds[rb + m + 1] = km;                  // out[..., m+1] = km
        float z = 1.0f - km * km;
        float r = 1.0f / z;                    // exact IEEE div — numerics-critical
        const int h = m >> 1;
        #pragma unroll
        for (int j = 0; j < h; ++j) {          // symmetric in-place pair update
            float x = ar[j], y = ar[m - 1 - j];
            ar[j]         = (x - km * y) * r;
            ar[m - 1 - j] = (y - km * x) * r;
        }
        if (m & 1)                              // middle element (j == m-1-j)
            ar[h] = (ar[h] - km * ar[h]) * r;
    }
    lds[rb + 1] = ar[0];                       // out[..., 1] = k0
    // lds[rb + 0] still holds K untouched.
    __syncthreads();

    // --- coalesced LDS -> global, vectorized ---
    if (full) {
        float4* o4 = (float4*)(out + base);
        const float4* lds4 = (const float4*)lds;
        #pragma unroll
        for (int k = 0; k < V4_ROUNDS; ++k)
            o4[t + k * TPB] = lds4[t + k * TPB];
        out[base + V4_ROUNDS * 4 * TPB + t] = lds[V4_ROUNDS * 4 * TPB + t];
    } else {
        for (int k = 0; k < NC; ++k) {
            int g = t + k * TPB;
            long long ga = base + g;
            if (ga < limit) out[ga] = lds[g];
        }
    }
}

extern "C" void kernel_launch(void* const* d_in, const int* in_sizes, int n_in,
                              void* d_out, int out_size, void* d_ws, size_t ws_size,
                              hipStream_t stream) {
    const float* a = (const float*)d_in[0];
    float* out = (float*)d_out;
    long long nrows = (long long)in_sizes[0] / NC;
    long long blocks = (nrows + TPB - 1) / TPB;
    lpc_to_parcor_kernel<<<(int)blocks, TPB, 0, stream>>>(a, out, nrows);
}

// Round 4
// 94.799 us; speedup vs baseline: 2.8467x; 1.1536x over previous
//
#include <hip/hip_runtime.h>

#define M 32                        // reflection coeffs
#define NC 33                       // floats per row
#define TPB 128                     // threads (rows) per tile
#define FPB (TPB * NC)              // 4224 floats per tile
#define V4 8                        // float4 rounds per thread (4096 floats)
#define TAIL (V4 * 4 * TPB)         // 4096: tail scalar index base

typedef float f4 __attribute__((ext_vector_type(4)));

// Levinson step-down for one row staged at lds[rb .. rb+32].
// Writes k_m into lds[rb+m+1]; lds[rb+0] (K) left untouched.
__device__ __forceinline__ void levinson(float* __restrict__ lds, int rb) {
    float ar[M];
#pragma unroll
    for (int j = 0; j < M; ++j) ar[j] = lds[rb + 1 + j];   // GAMMA == 1.0
#pragma unroll
    for (int m = M - 1; m >= 1; --m) {
        float km = ar[m];
        lds[rb + m + 1] = km;
        float z = 1.0f - km * km;
        float r = 1.0f / z;          // exact IEEE div — numerics-critical (R2 lesson)
        const int h = m >> 1;
#pragma unroll
        for (int j = 0; j < h; ++j) {
            float x = ar[j], y = ar[m - 1 - j];
            ar[j]         = (x - km * y) * r;
            ar[m - 1 - j] = (y - km * x) * r;
        }
        if (m & 1) ar[h] = (ar[h] - km * ar[h]) * r;
    }
    lds[rb + 1] = ar[0];
}

__device__ __forceinline__ void load_tile_full(float* __restrict__ lds,
                                               const float* __restrict__ src, int t) {
    const f4* a4 = (const f4*)src;
    f4* l4 = (f4*)lds;
#pragma unroll
    for (int k = 0; k < V4; ++k) l4[t + k * TPB] = a4[t + k * TPB];
    lds[TAIL + t] = src[TAIL + t];
}

__device__ __forceinline__ void store_tile_nt(float* __restrict__ dst,
                                              const float* __restrict__ lds, int t) {
    const f4* l4 = (const f4*)lds;
#pragma unroll
    for (int k = 0; k < V4; ++k) {
        f4 v = l4[t + k * TPB];
        __builtin_nontemporal_store(v, (f4*)dst + t + k * TPB);
    }
    __builtin_nontemporal_store(lds[TAIL + t], dst + TAIL + t);
}

// guarded slow path for a (possibly partial) tile
__device__ __forceinline__ void process_tile_guarded(float* __restrict__ lds,
                                                     const float* __restrict__ a,
                                                     float* __restrict__ out,
                                                     long long base, long long limit, int t) {
    for (int k = 0; k < NC; ++k) {
        int g = t + k * TPB;
        long long ga = base + g;
        lds[g] = (ga < limit) ? a[ga] : 0.0f;
    }
    __syncthreads();
    levinson(lds, t * NC);
    __syncthreads();
    for (int k = 0; k < NC; ++k) {
        int g = t + k * TPB;
        long long ga = base + g;
        if (ga < limit) out[ga] = lds[g];
    }
    __syncthreads();
}

__global__ __launch_bounds__(TPB)
void lpc_to_parcor_kernel(const float* __restrict__ a,
                          float* __restrict__ out,
                          long long nrows) {
    __shared__ float lds[FPB];
    const int t = threadIdx.x;
    const long long limit = nrows * NC;
    const long long base0 = (long long)blockIdx.x * 2 * FPB;
    const long long base1 = base0 + FPB;
    const bool full0 = (base0 + FPB) <= limit;
    const bool full1 = (base1 + FPB) <= limit;

    if (full0 && full1) {
        // ---------- pipelined fast path: 2 tiles ----------
        load_tile_full(lds, a + base0, t);
        __syncthreads();

        // issue tile1 global loads -> regs; pin issue point so the
        // compiler can't sink them below the compute phase
        f4 p[V4]; float pt;
        {
            const f4* b4 = (const f4*)(a + base1);
#pragma unroll
            for (int k = 0; k < V4; ++k) p[k] = b4[t + k * TPB];
            pt = a[base1 + TAIL + t];
        }
        __builtin_amdgcn_sched_barrier(0);

        levinson(lds, t * NC);          // tile1 HBM latency hides under this
        __syncthreads();

        store_tile_nt(out + base0, lds, t);
        __syncthreads();                // LDS reads for store done before overwrite

        {
            f4* l4 = (f4*)lds;
#pragma unroll
            for (int k = 0; k < V4; ++k) l4[t + k * TPB] = p[k];
            lds[TAIL + t] = pt;
        }
        __syncthreads();

        levinson(lds, t * NC);
        __syncthreads();

        store_tile_nt(out + base1, lds, t);
    } else {
        // ---------- guarded tail path ----------
        if (base0 < limit) process_tile_guarded(lds, a, out, base0, limit, t);
        if (base1 < limit) process_tile_guarded(lds, a, out, base1, limit, t);
    }
}

extern "C" void kernel_launch(void* const* d_in, const int* in_sizes, int n_in,
                              void* d_out, int out_size, void* d_ws, size_t ws_size,
                              hipStream_t stream) {
    const float* a = (const float*)d_in[0];
    float* out = (float*)d_out;
    long long nrows = (long long)in_sizes[0] / NC;
    long long tiles = (nrows + TPB - 1) / TPB;
    long long blocks = (tiles + 1) / 2;
    lpc_to_parcor_kernel<<<(int)blocks, TPB, 0, stream>>>(a, out, nrows);
}